// Round 1
// baseline (244.253 us; speedup 1.0000x reference)
//
#include <hip/hip_runtime.h>

// ConvSoftArgmax2d: x (8,16,512,512) fp32 -> coords (128,2,256,256), resp (128,1,256,256)
// 3x3 window, stride 2, pad 1. Zero padding applied to exp(x/T) (not exp(0)).
// Only r=-1 / c=-1 can be out of bounds (top/left edges).

#define H  512
#define W  512
#define HO 256
#define WO 256
#define BC 128

__global__ __launch_bounds__(256) void casm_kernel(
    const float* __restrict__ x, const float* __restrict__ temp,
    float* __restrict__ out)
{
    int idx = blockIdx.x * 256 + threadIdx.x;
    int wo = idx & (WO - 1);
    int ho = (idx >> 8) & (HO - 1);
    int bc = idx >> 16;

    float invT = 1.0f / fmaxf(temp[0], 1e-8f);

    const float* __restrict__ xp = x + (size_t)bc * (H * W);
    int r0 = 2 * ho - 1;
    int c0 = 2 * wo - 1;

    float den = 1e-12f;
    float num_v = 0.f, num_gx = 0.f, num_gy = 0.f;

#pragma unroll
    for (int kh = 0; kh < 3; ++kh) {
        int r = r0 + kh;
        if (r < 0) continue;                 // r > 511 impossible
        const float* __restrict__ row = xp + r * W;
#pragma unroll
        for (int kw = 0; kw < 3; ++kw) {
            int c = c0 + kw;
            if (c < 0) continue;             // c > 511 impossible
            float v = row[c];
            float e = expf(v * invT);
            den    += e;
            num_v  += e * v;
            num_gx += e * (float)(kw - 1);
            num_gy += e * (float)(kh - 1);
        }
    }

    float inv_den = 1.0f / den;
    const float scale = 2.0f / 511.0f;
    float cx   = (num_gx * inv_den + (float)(2 * wo)) * scale - 1.0f;
    float cy   = (num_gy * inv_den + (float)(2 * ho)) * scale - 1.0f;
    float resp = num_v * inv_den;

    size_t pix   = (size_t)ho * WO + wo;
    size_t cbase = (size_t)bc * (2 * HO * WO) + pix;
    out[cbase]            = cx;                                   // channel 0: x
    out[cbase + HO * WO]  = cy;                                   // channel 1: y
    out[(size_t)BC * 2 * HO * WO + (size_t)bc * HO * WO + pix] = resp;
}

extern "C" void kernel_launch(void* const* d_in, const int* in_sizes, int n_in,
                              void* d_out, int out_size, void* d_ws, size_t ws_size,
                              hipStream_t stream) {
    const float* x    = (const float*)d_in[0];
    const float* temp = (const float*)d_in[1];
    float* out        = (float*)d_out;

    int total  = BC * HO * WO;          // 8,388,608 output pixels
    int blocks = total / 256;           // 32768
    casm_kernel<<<blocks, 256, 0, stream>>>(x, temp, out);
}

// Round 2
// 219.102 us; speedup vs baseline: 1.1148x; 1.1148x over previous
//
#include <hip/hip_runtime.h>

// ConvSoftArgmax2d: x (8,16,512,512) fp32 -> coords (128,2,256,256), resp (128,1,256,256)
// 3x3 window, stride 2, pad 1. Padding contributes 0 to the pooled exp-sums.
// Only r=-1 (ho==0, block-uniform) and c=-1 (wo==0, one lane) are out of bounds.

#define H  512
#define W  512
#define HO 256
#define WO 256
#define BC 128

__global__ __launch_bounds__(256) void casm_kernel(
    const float* __restrict__ x, const float* __restrict__ temp,
    float* __restrict__ out)
{
    int idx = blockIdx.x * 256 + threadIdx.x;
    int wo = idx & (WO - 1);
    int ho = (idx >> 8) & (HO - 1);   // block-uniform (256 threads = one wo-row)
    int bc = idx >> 16;

    // exp(v/T) = exp2(v * log2e / T)
    float k = 1.44269504088896340736f / fmaxf(temp[0], 1e-8f);

    const float* __restrict__ xp = x + (size_t)bc * (H * W);
    int r0 = 2 * ho - 1;
    int c0 = 2 * wo - 1;              // left column; only one that can be <0
    int cL = c0 < 0 ? 0 : c0;
    float mL = c0 < 0 ? 0.0f : 1.0f;  // left-column mask
    int cM = 2 * wo;                  // middle/right pair, 8B-aligned

    float s0 = 0.f, s1, s2;           // per-row exp sums
    float colL = 0.f, colR = 0.f, numv = 0.f;

    // row 0 (may be padded; condition is block-uniform)
    if (r0 >= 0) {
        const float* __restrict__ row = xp + r0 * W;
        float  v0 = row[cL];
        float2 v12 = *(const float2*)(row + cM);
        float e0 = mL * __builtin_amdgcn_exp2f(k * v0);
        float e1 = __builtin_amdgcn_exp2f(k * v12.x);
        float e2 = __builtin_amdgcn_exp2f(k * v12.y);
        s0 = e0 + e1 + e2;
        colL += e0; colR += e2;
        numv = fmaf(e0, v0, fmaf(e1, v12.x, fmaf(e2, v12.y, numv)));
    }
    // row 1 (always in bounds: 2*ho in [0,510])
    {
        const float* __restrict__ row = xp + (r0 + 1) * W;
        float  v0 = row[cL];
        float2 v12 = *(const float2*)(row + cM);
        float e0 = mL * __builtin_amdgcn_exp2f(k * v0);
        float e1 = __builtin_amdgcn_exp2f(k * v12.x);
        float e2 = __builtin_amdgcn_exp2f(k * v12.y);
        s1 = e0 + e1 + e2;
        colL += e0; colR += e2;
        numv = fmaf(e0, v0, fmaf(e1, v12.x, fmaf(e2, v12.y, numv)));
    }
    // row 2 (always in bounds: 2*ho+1 <= 511)
    {
        const float* __restrict__ row = xp + (r0 + 2) * W;
        float  v0 = row[cL];
        float2 v12 = *(const float2*)(row + cM);
        float e0 = mL * __builtin_amdgcn_exp2f(k * v0);
        float e1 = __builtin_amdgcn_exp2f(k * v12.x);
        float e2 = __builtin_amdgcn_exp2f(k * v12.y);
        s2 = e0 + e1 + e2;
        colL += e0; colR += e2;
        numv = fmaf(e0, v0, fmaf(e1, v12.x, fmaf(e2, v12.y, numv)));
    }

    float den = s0 + s1 + s2 + 1e-12f;
    float inv_den = __builtin_amdgcn_rcpf(den);
    const float scale = 2.0f / 511.0f;
    float cx   = ((colR - colL) * inv_den + (float)(2 * wo)) * scale - 1.0f;
    float cy   = ((s2 - s0)    * inv_den + (float)(2 * ho)) * scale - 1.0f;
    float resp = numv * inv_den;

    size_t pix   = (size_t)ho * WO + wo;
    size_t cbase = (size_t)bc * (2 * HO * WO) + pix;
    out[cbase]           = cx;                                     // channel 0: x
    out[cbase + HO * WO] = cy;                                     // channel 1: y
    out[(size_t)BC * 2 * HO * WO + (size_t)bc * HO * WO + pix] = resp;
}

extern "C" void kernel_launch(void* const* d_in, const int* in_sizes, int n_in,
                              void* d_out, int out_size, void* d_ws, size_t ws_size,
                              hipStream_t stream) {
    const float* x    = (const float*)d_in[0];
    const float* temp = (const float*)d_in[1];
    float* out        = (float*)d_out;

    int total  = BC * HO * WO;          // 8,388,608 output pixels
    int blocks = total / 256;           // 32768
    casm_kernel<<<blocks, 256, 0, stream>>>(x, temp, out);
}